// Round 3
// baseline (60.474 us; speedup 1.0000x reference)
//
#include <hip/hip_runtime.h>

#define NNODES 2048
#define NHEADS 8
#define NN (NNODES * NNODES)

#define WINNER_BYTES ((size_t)NN * sizeof(int))  // 16 MiB

typedef int   vint4   __attribute__((ext_vector_type(4)));
typedef float vfloat4 __attribute__((ext_vector_type(4)));

// Fill winner with -1 (one vint4 per thread; 1M threads cover 16 MiB).
__global__ __launch_bounds__(256) void fill_kernel(vint4* __restrict__ winner) {
    int t = blockIdx.x * blockDim.x + threadIdx.x;
    vint4 m1 = {-1, -1, -1, -1};
    __builtin_nontemporal_store(m1, winner + t);
}

// Per-edge pass: resolve duplicates (last edge index wins, matching numpy
// scatter-set) AND precompute the 8 sigmoid values per edge into vals[e][8].
__global__ __launch_bounds__(256) void edge_kernel(const int* __restrict__ ei,
                                                   const float* __restrict__ edge_score,
                                                   const float* __restrict__ W,
                                                   const float* __restrict__ b,
                                                   int E,
                                                   int* __restrict__ winner,
                                                   float* __restrict__ vals) {
    int e = blockIdx.x * blockDim.x + threadIdx.x;
    if (e >= E) return;
    const int row = ei[e];
    const int col = ei[E + e];
    atomicMax(&winner[row * NNODES + col], e);

    const float fr = (float)row, fc = (float)col, sc = edge_score[e];
    float v[NHEADS];
#pragma unroll
    for (int h = 0; h < NHEADS; ++h) {
        const float x = fmaf(fr, W[3 * h + 0],
                        fmaf(fc, W[3 * h + 1],
                        fmaf(sc, W[3 * h + 2], b[h])));
        v[h] = 1.0f / (1.0f + __expf(-x));
    }
    vfloat4* vv = reinterpret_cast<vfloat4*>(vals + (size_t)e * NHEADS);
    vfloat4 lo = {v[0], v[1], v[2], v[3]};
    vfloat4 hi = {v[4], v[5], v[6], v[7]};
    vv[0] = lo;
    vv[1] = hi;
}

// Dense write: pure data movement. 4 cells/thread, 8 heads -> 8 vfloat4 NT
// stores. Gathers are exec-masked: ~94% of cells issue no vals load.
__global__ __launch_bounds__(256) void write_kernel(const int* __restrict__ winner,
                                                    const float* __restrict__ vals,
                                                    float* __restrict__ out) {
    int t = blockIdx.x * blockDim.x + threadIdx.x;
    int cell0 = t << 2;

    const vint4 w4 = __builtin_nontemporal_load(
        reinterpret_cast<const vint4*>(winner + cell0));
    const int wi[4] = {w4.x, w4.y, w4.z, w4.w};

    float va[4][NHEADS];
#pragma unroll
    for (int i = 0; i < 4; ++i) {
        vfloat4 lo = {0.f, 0.f, 0.f, 0.f};
        vfloat4 hi = lo;
        if (wi[i] >= 0) {
            const vfloat4* vv = reinterpret_cast<const vfloat4*>(vals + (size_t)wi[i] * NHEADS);
            lo = vv[0];
            hi = vv[1];
        }
        va[i][0] = lo.x; va[i][1] = lo.y; va[i][2] = lo.z; va[i][3] = lo.w;
        va[i][4] = hi.x; va[i][5] = hi.y; va[i][6] = hi.z; va[i][7] = hi.w;
    }
#pragma unroll
    for (int h = 0; h < NHEADS; ++h) {
        const vfloat4 v = {va[0][h], va[1][h], va[2][h], va[3][h]};
        __builtin_nontemporal_store(v,
            reinterpret_cast<vfloat4*>(out + (size_t)h * NN + cell0));
    }
}

// Fallback (ws too small for vals): compute-in-place per cell.
__global__ __launch_bounds__(256) void write_kernel_fb(const int* __restrict__ winner,
                                                       const float* __restrict__ edge_score,
                                                       const float* __restrict__ W,
                                                       const float* __restrict__ b,
                                                       float* __restrict__ out) {
    int t = blockIdx.x * blockDim.x + threadIdx.x;
    int cell0 = t << 2;
    const vint4 w4 = *reinterpret_cast<const vint4*>(winner + cell0);
    const int wi[4] = {w4.x, w4.y, w4.z, w4.w};
    const float row  = (float)(cell0 >> 11);
    const float colb = (float)(cell0 & (NNODES - 1));
    float sc[4];
#pragma unroll
    for (int i = 0; i < 4; ++i) sc[i] = (wi[i] >= 0) ? edge_score[wi[i]] : 0.0f;
#pragma unroll
    for (int h = 0; h < NHEADS; ++h) {
        const float W0 = W[h * 3 + 0], W1 = W[h * 3 + 1], W2 = W[h * 3 + 2], B = b[h];
        vfloat4 v;
#pragma unroll
        for (int i = 0; i < 4; ++i) {
            const float x = fmaf(row, W0, fmaf(colb + (float)i, W1, fmaf(sc[i], W2, B)));
            const float s = 1.0f / (1.0f + __expf(-x));
            v[i] = (wi[i] >= 0) ? s : 0.0f;
        }
        __builtin_nontemporal_store(v,
            reinterpret_cast<vfloat4*>(out + (size_t)h * NN + cell0));
    }
}

extern "C" void kernel_launch(void* const* d_in, const int* in_sizes, int n_in,
                              void* d_out, int out_size, void* d_ws, size_t ws_size,
                              hipStream_t stream) {
    const int*   edge_index = (const int*)d_in[0];   // (2, E) int32
    const float* edge_score = (const float*)d_in[1]; // (E,)
    const float* W          = (const float*)d_in[2]; // (H, 3)
    const float* b          = (const float*)d_in[3]; // (H,)
    float*       out        = (float*)d_out;         // (H, N, N)
    const int E = in_sizes[1];

    int*   winner = (int*)d_ws;
    float* vals   = (float*)((char*)d_ws + WINNER_BYTES);
    const bool have_vals = ws_size >= WINNER_BYTES + (size_t)E * NHEADS * sizeof(float);

    fill_kernel<<<NN / (4 * 256), 256, 0, stream>>>((vint4*)winner);

    if (have_vals) {
        edge_kernel<<<(E + 255) / 256, 256, 0, stream>>>(edge_index, edge_score, W, b,
                                                         E, winner, vals);
        write_kernel<<<NN / (4 * 256), 256, 0, stream>>>(winner, vals, out);
    } else {
        // No vals buffer: just resolve winners, then compute in the write pass.
        edge_kernel<<<(E + 255) / 256, 256, 0, stream>>>(edge_index, edge_score, W, b,
                                                         E, winner,
                                                         /*vals=*/(float*)winner /*unused dummy? no*/);
        write_kernel_fb<<<NN / (4 * 256), 256, 0, stream>>>(winner, edge_score, W, b, out);
    }
}

// Round 4
// 53.280 us; speedup vs baseline: 1.1350x; 1.1350x over previous
//
#include <hip/hip_runtime.h>

#define NNODES 2048
#define NHEADS 8
#define NN (NNODES * NNODES)

#define WINNER_BYTES ((size_t)NN * sizeof(int))  // 16 MiB

typedef int   vint4   __attribute__((ext_vector_type(4)));
typedef float vfloat4 __attribute__((ext_vector_type(4)));

// Fill winner with -1 (one vint4 per thread; 1M threads cover 16 MiB).
// Plain (cache-allocating) stores so the atomic pass hits cache, not HBM.
__global__ __launch_bounds__(256) void fill_kernel(vint4* __restrict__ winner) {
    int t = blockIdx.x * blockDim.x + threadIdx.x;
    vint4 m1 = {-1, -1, -1, -1};
    winner[t] = m1;
}

// Per-edge pass: resolve duplicates (last edge index wins, matching numpy
// scatter-set) AND precompute the 8 sigmoid values per edge into vals[e][8].
__global__ __launch_bounds__(256) void edge_kernel(const int* __restrict__ ei,
                                                   const float* __restrict__ edge_score,
                                                   const float* __restrict__ W,
                                                   const float* __restrict__ b,
                                                   int E,
                                                   int* __restrict__ winner,
                                                   float* __restrict__ vals) {
    int e = blockIdx.x * blockDim.x + threadIdx.x;
    if (e >= E) return;
    const int row = ei[e];
    const int col = ei[E + e];
    atomicMax(&winner[row * NNODES + col], e);

    const float fr = (float)row, fc = (float)col, sc = edge_score[e];
    float v[NHEADS];
#pragma unroll
    for (int h = 0; h < NHEADS; ++h) {
        const float x = fmaf(fr, W[3 * h + 0],
                        fmaf(fc, W[3 * h + 1],
                        fmaf(sc, W[3 * h + 2], b[h])));
        v[h] = 1.0f / (1.0f + __expf(-x));
    }
    vfloat4* vv = reinterpret_cast<vfloat4*>(vals + (size_t)e * NHEADS);
    vfloat4 lo = {v[0], v[1], v[2], v[3]};
    vfloat4 hi = {v[4], v[5], v[6], v[7]};
    vv[0] = lo;
    vv[1] = hi;
}

// Dense write: pure data movement. 4 cells/thread, 8 heads -> 8 float4
// stores. Gathers are exec-masked: ~94% of cells issue no vals load.
__global__ __launch_bounds__(256) void write_kernel(const int* __restrict__ winner,
                                                    const float* __restrict__ vals,
                                                    float* __restrict__ out) {
    int t = blockIdx.x * blockDim.x + threadIdx.x;
    int cell0 = t << 2;

    const vint4 w4 = *reinterpret_cast<const vint4*>(winner + cell0);
    const int wi[4] = {w4.x, w4.y, w4.z, w4.w};

    float va[4][NHEADS];
#pragma unroll
    for (int i = 0; i < 4; ++i) {
        vfloat4 lo = {0.f, 0.f, 0.f, 0.f};
        vfloat4 hi = lo;
        if (wi[i] >= 0) {
            const vfloat4* vv = reinterpret_cast<const vfloat4*>(vals + (size_t)wi[i] * NHEADS);
            lo = vv[0];
            hi = vv[1];
        }
        va[i][0] = lo.x; va[i][1] = lo.y; va[i][2] = lo.z; va[i][3] = lo.w;
        va[i][4] = hi.x; va[i][5] = hi.y; va[i][6] = hi.z; va[i][7] = hi.w;
    }
#pragma unroll
    for (int h = 0; h < NHEADS; ++h) {
        const vfloat4 v = {va[0][h], va[1][h], va[2][h], va[3][h]};
        *reinterpret_cast<vfloat4*>(out + (size_t)h * NN + cell0) = v;
    }
}

// Fallback (ws too small for vals): compute-in-place per cell.
__global__ __launch_bounds__(256) void write_kernel_fb(const int* __restrict__ winner,
                                                       const float* __restrict__ edge_score,
                                                       const float* __restrict__ W,
                                                       const float* __restrict__ b,
                                                       float* __restrict__ out) {
    int t = blockIdx.x * blockDim.x + threadIdx.x;
    int cell0 = t << 2;
    const vint4 w4 = *reinterpret_cast<const vint4*>(winner + cell0);
    const int wi[4] = {w4.x, w4.y, w4.z, w4.w};
    const float row  = (float)(cell0 >> 11);
    const float colb = (float)(cell0 & (NNODES - 1));
    float sc[4];
#pragma unroll
    for (int i = 0; i < 4; ++i) sc[i] = (wi[i] >= 0) ? edge_score[wi[i]] : 0.0f;
#pragma unroll
    for (int h = 0; h < NHEADS; ++h) {
        const float W0 = W[h * 3 + 0], W1 = W[h * 3 + 1], W2 = W[h * 3 + 2], B = b[h];
        vfloat4 v;
#pragma unroll
        for (int i = 0; i < 4; ++i) {
            const float x = fmaf(row, W0, fmaf(colb + (float)i, W1, fmaf(sc[i], W2, B)));
            const float s = 1.0f / (1.0f + __expf(-x));
            v[i] = (wi[i] >= 0) ? s : 0.0f;
        }
        *reinterpret_cast<vfloat4*>(out + (size_t)h * NN + cell0) = v;
    }
}

extern "C" void kernel_launch(void* const* d_in, const int* in_sizes, int n_in,
                              void* d_out, int out_size, void* d_ws, size_t ws_size,
                              hipStream_t stream) {
    const int*   edge_index = (const int*)d_in[0];   // (2, E) int32
    const float* edge_score = (const float*)d_in[1]; // (E,)
    const float* W          = (const float*)d_in[2]; // (H, 3)
    const float* b          = (const float*)d_in[3]; // (H,)
    float*       out        = (float*)d_out;         // (H, N, N)
    const int E = in_sizes[1];

    int*   winner = (int*)d_ws;
    float* vals   = (float*)((char*)d_ws + WINNER_BYTES);
    const bool have_vals = ws_size >= WINNER_BYTES + (size_t)E * NHEADS * sizeof(float);

    fill_kernel<<<NN / (4 * 256), 256, 0, stream>>>((vint4*)winner);

    edge_kernel<<<(E + 255) / 256, 256, 0, stream>>>(edge_index, edge_score, W, b,
                                                     E, winner, vals);
    if (have_vals) {
        write_kernel<<<NN / (4 * 256), 256, 0, stream>>>(winner, vals, out);
    } else {
        write_kernel_fb<<<NN / (4 * 256), 256, 0, stream>>>(winner, edge_score, W, b, out);
    }
}